// Round 1
// baseline (230.236 us; speedup 1.0000x reference)
//
#include <hip/hip_runtime.h>
#include <math.h>

#define BB 16
#define NN 2048
#define FF 64
#define SS 4
#define PP 22
#define OO 42
#define FPDIM (FF + 2*PP)   // 108
#define NREG 32             // all 2048/64 d2 values kept in VGPRs per lane
#define CAP 256             // LDS candidate-list capacity per wave
#define PREBLK 128                     // blocks 0..127: coords/feats rows
#define XWOBLK ((BB*NN*21 + 255)/256)  // 2688 blocks: xwo o-pairs

__device__ __forceinline__ float readfirstlane_f32(float v) {
    // value-preserving wave-uniform broadcast (builtin is int->int; must pass bits!)
    return __uint_as_float((unsigned)__builtin_amdgcn_readfirstlane((int)__float_as_uint(v)));
}

// count of set bits below my lane (v_mbcnt_lo + v_mbcnt_hi, 2 VALU)
__device__ __forceinline__ int lane_prefix(unsigned long long m) {
    return __builtin_amdgcn_mbcnt_hi((unsigned)(m >> 32),
           __builtin_amdgcn_mbcnt_lo((unsigned)m, 0u));
}

// float wave sum via DPP chain (0-bits = 0.0f additive identity)
__device__ __forceinline__ float wave_fsum_dpp(float x) {
    float t;
    t = __uint_as_float((unsigned)__builtin_amdgcn_update_dpp(0, (int)__float_as_uint(x), 0x111, 0xf, 0xf, true)); x += t;
    t = __uint_as_float((unsigned)__builtin_amdgcn_update_dpp(0, (int)__float_as_uint(x), 0x112, 0xf, 0xf, true)); x += t;
    t = __uint_as_float((unsigned)__builtin_amdgcn_update_dpp(0, (int)__float_as_uint(x), 0x114, 0xf, 0xf, true)); x += t;
    t = __uint_as_float((unsigned)__builtin_amdgcn_update_dpp(0, (int)__float_as_uint(x), 0x118, 0xf, 0xf, true)); x += t;
    t = __uint_as_float((unsigned)__builtin_amdgcn_update_dpp(0, (int)__float_as_uint(x), 0x142, 0xa, 0xf, true)); x += t;
    t = __uint_as_float((unsigned)__builtin_amdgcn_update_dpp(0, (int)__float_as_uint(x), 0x143, 0xc, 0xf, true)); x += t;
    return __uint_as_float((unsigned)__builtin_amdgcn_readlane((int)__float_as_uint(x), 63));
}

// ---- Kernel 1 (fused): blocks 0..127 -> coords/feats rows; blocks 128.. -> xwo o-pairs ----
__global__ __launch_bounds__(256) void prep_kernel(
    const float* __restrict__ x, const float* __restrict__ Ws, const float* __restrict__ bs,
    const float* __restrict__ Wf, const float* __restrict__ bf,
    const float* __restrict__ Wo, const float* __restrict__ bo,
    float* __restrict__ coords, float* __restrict__ feats, float* __restrict__ xwo)
{
    if (blockIdx.x >= PREBLK) {
        // ---- xwo[row][2p..2p+1] = x[row] . Wo[:64, 2p..2p+1] + bo ----
        int idx = (blockIdx.x - PREBLK) * 256 + threadIdx.x;   // row*21 + p
        if (idx >= BB * NN * 21) return;
        int row = idx / 21;                // magic-mul division
        int p   = idx - row * 21;
        int o   = p * 2;
        const float4* xr = (const float4*)(x + (size_t)row * FF);
        float a0 = bo[o], b0 = bo[o + 1], a1 = 0.f, b1 = 0.f;
        #pragma unroll
        for (int k4 = 0; k4 < FF / 4; k4++) {
            float4 xv = xr[k4];            // broadcast within row-group of lanes
            const float* wb = Wo + (k4 * 4) * OO + o;
            float2 w0 = *((const float2*)(wb));
            float2 w1 = *((const float2*)(wb + OO));
            float2 w2 = *((const float2*)(wb + 2 * OO));
            float2 w3 = *((const float2*)(wb + 3 * OO));
            a0 = fmaf(xv.x, w0.x, a0); b0 = fmaf(xv.x, w0.y, b0);
            a1 = fmaf(xv.y, w1.x, a1); b1 = fmaf(xv.y, w1.y, b1);
            a0 = fmaf(xv.z, w2.x, a0); b0 = fmaf(xv.z, w2.y, b0);
            a1 = fmaf(xv.w, w3.x, a1); b1 = fmaf(xv.w, w3.y, b1);
        }
        *((float2*)(xwo + (size_t)idx * 2)) = make_float2(a0 + a1, b0 + b1);   // coalesced
        return;
    }

    // ---- coords = x@W_s + b_s ; feats = x@W_f + b_f ----
    int row = blockIdx.x * 256 + threadIdx.x;   // 0 .. B*N-1
    if (row >= BB * NN) return;

    const float4* x4 = (const float4*)(x + (size_t)row * FF);
    float c0 = bs[0], c1 = bs[1], c2 = bs[2], c3 = bs[3];
    float f[PP];
    #pragma unroll
    for (int c = 0; c < PP; c++) f[c] = bf[c];

    #pragma unroll
    for (int k4 = 0; k4 < FF / 4; k4++) {
        float4 xv = x4[k4];
        float xs[4] = {xv.x, xv.y, xv.z, xv.w};
        #pragma unroll
        for (int r = 0; r < 4; r++) {
            int k = k4 * 4 + r;
            float xk = xs[r];
            c0 = fmaf(xk, Ws[k * SS + 0], c0);
            c1 = fmaf(xk, Ws[k * SS + 1], c1);
            c2 = fmaf(xk, Ws[k * SS + 2], c2);
            c3 = fmaf(xk, Ws[k * SS + 3], c3);
            #pragma unroll
            for (int c = 0; c < PP; c++) f[c] = fmaf(xk, Wf[k * PP + c], f[c]);
        }
    }
    float4* cp = (float4*)(coords + (size_t)row * SS);
    *cp = make_float4(c0, c1, c2, c3);
    float* fo = feats + (size_t)row * PP;
    #pragma unroll
    for (int c = 0; c < PP; c++) fo[c] = f[c];
}

// ---- Kernel 2: wave-per-query kNN via compact-then-select + fused output ----
// R15 restructure: the old quad-probe + register-bisection + collect (4-5 VALU passes
// over 32 d2 regs, ~800 instr/wave) is replaced by ONE ballot/mbcnt compaction pass
// (elements with d2 < 1.5*t0 -> LDS u64 key list, counts on the scalar pipe), then all
// refinement (bisect / split / rank) runs on the ~90-entry list (1-4 keys per lane).
// u32 compares on d2 bits == f32 compares (d2 >= 0). key = (d2bits<<32)|j matches
// top_k's tie-by-lower-index. Bits-bracketed retry handles threshold under/overflow.
__global__ __launch_bounds__(128, 4) void knn_out_kernel(
    const float* __restrict__ coords, const float* __restrict__ feats,
    const float* __restrict__ xwo, const float* __restrict__ Wo,
    const int* __restrict__ nnbr, float* __restrict__ out)
{
    const int lane = threadIdx.x & 63;
    const int w    = threadIdx.x >> 6;
    const int q    = blockIdx.x * 2 + w;       // 0..32767
    const int b    = q >> 11;
    const int i    = q & (NN - 1);

    int K = *nnbr; K = K < 2 ? 2 : (K > 64 ? 64 : K);

    __shared__ unsigned long long list[2][CAP];   // compacted (d2bits<<32)|j keys
    __shared__ unsigned long long candk[2][64];   // window candidates (raw keys)
    __shared__ unsigned long long selk[2][64];    // selected {hi=d2bits->weight, lo=j*PP}
    __shared__ __align__(16) float urow[2][48];   // [max | mean], 44 used

    // prefetch the precomputed x-part of the output (overlaps the distance phase)
    float xw = 0.f;
    if (lane < OO) xw = xwo[(size_t)q * OO + lane];

    const float4* cb = (const float4*)(coords + (size_t)b * NN * SS);
    float4 qv = cb[i];
    const float qx = readfirstlane_f32(qv.x);
    const float qy = readfirstlane_f32(qv.y);
    const float qz = readfirstlane_f32(qv.z);
    const float qw = readfirstlane_f32(qv.w);

    // ---- pass 1: all 2048 d2 kept in 32 VGPRs/lane; track per-lane min ----
    float d2r[NREG];
    float lmin = INFINITY;
    #pragma unroll 4
    for (int r = 0; r < NREG; r++) {
        float4 c = cb[r * 64 + lane];
        float d0 = qx - c.x, d1 = qy - c.y, d2 = qz - c.z, d3 = qw - c.w;
        float v = d0 * d0 + d1 * d1 + d2 * d2 + d3 * d3;
        d2r[r] = v;
        lmin = fminf(lmin, v);
    }

    // mean of per-lane minima ~ 1.5% quantile ~ K/N quantile
    float t0 = wave_fsum_dpp(lmin) * (1.0f / 64.0f);
    if (!(t0 > 1e-30f)) t0 = 1e-30f;

    // ---- pass 2: compact d2 < tc into LDS; count d2 < tin on the scalar pipe ----
    unsigned tinU = __float_as_uint(t0);          // inner count threshold (~K expected)
    unsigned tcU  = __float_as_uint(t0 * 1.5f);   // compaction threshold (~2.25K expected)
    unsigned bLoU = 0u;                           // bracket: count(<bLo) <  K
    unsigned bHiU = 0x7F800000u;                  // bracket: count(<bHi) > CAP
    int c_in = 0, c_tc = 0;

    for (int att = 0; att < 40; att++) {
        int sb = 0, ci = 0;
        #pragma unroll
        for (int r = 0; r < NREG; r++) {
            unsigned vb = __float_as_uint(d2r[r]);
            ci += (int)__popcll(__ballot(vb < tinU));        // SALU popcount+add
            unsigned long long m = __ballot(vb < tcU);
            if (vb < tcU) {
                int pos = sb + lane_prefix(m);
                if (pos < CAP)
                    list[w][pos] = ((unsigned long long)vb << 32) | (unsigned)(r * 64 + lane);
            }
            sb += (int)__popcll(m);
        }
        c_in = ci; c_tc = sb;
        if (c_tc >= K && c_tc <= CAP) break;      // list valid & complete below tc
        if (c_tc < K) {                           // underflow: grow tc (rare)
            bLoU = tcU; tinU = tcU;
            unsigned prop = __float_as_uint(__uint_as_float(tcU) * 3.0f);
            if (prop <= bLoU || prop >= bHiU) prop = bLoU + ((bHiU - bLoU) >> 1);
            if (prop <= bLoU) prop = bLoU + 1u;
            tcU = prop;
        } else {                                  // overflow: shrink tc (rare)
            bHiU = tcU;
            unsigned prop = __float_as_uint(__uint_as_float(tcU) * 0.55f);
            if (prop <= bLoU || prop >= bHiU) prop = bLoU + ((bHiU - bLoU) >> 1);
            if (prop <= bLoU) prop = bLoU + 1u;
            tcU = prop;
            unsigned pin = __float_as_uint(__uint_as_float(tcU) * 0.62f);
            tinU = (pin < tcU) ? pin : (tcU - 1u);
        }
    }
    __builtin_amdgcn_wave_barrier();

    // ---- bracket with invariant cnt(<lo) < K <= cnt(<hi) ----
    unsigned loU, hiU; int cLo, cHi;
    if (c_in >= K) { loU = 0u;   cLo = 0;    hiU = tinU; cHi = c_in; }
    else           { loU = tinU; cLo = c_in; hiU = tcU;  cHi = c_tc; }

    // ---- load owned list keys (lane, lane+64, ...); ~0 sentinel never selects ----
    unsigned long long k0 = ~0ull, k1 = ~0ull, k2 = ~0ull, k3 = ~0ull;
    if (lane < c_tc)       k0 = list[w][lane];
    if (lane + 64 < c_tc)  k1 = list[w][lane + 64];
    if (c_tc > 128) {
        if (lane + 128 < c_tc) k2 = list[w][lane + 128];
        if (lane + 192 < c_tc) k3 = list[w][lane + 192];
    }

    // ---- bisect ON THE LIST until window <= 64 (interp / bits-midpoint alternate) ----
    int guard = 0;
    while (cHi - cLo > 64 && hiU - loU > 1u && guard < 24) {
        unsigned tmU;
        if (guard & 1) {
            tmU = loU + ((hiU - loU) >> 1);
        } else {
            float tLo = __uint_as_float(loU), tHi = __uint_as_float(hiU);
            float frac = (float)(K - cLo) / (float)(cHi - cLo);
            tmU = __float_as_uint(tLo + (tHi - tLo) * frac);
        }
        if (tmU <= loU) tmU = loU + 1u;
        if (tmU >= hiU) tmU = hiU - 1u;
        int cm = (int)__popcll(__ballot((unsigned)(k0 >> 32) < tmU))
               + (int)__popcll(__ballot((unsigned)(k1 >> 32) < tmU))
               + (int)__popcll(__ballot((unsigned)(k2 >> 32) < tmU))
               + (int)__popcll(__ballot((unsigned)(k3 >> 32) < tmU));
        if (cm >= K) { hiU = tmU; cHi = cm; } else { loU = tmU; cLo = cm; }
        guard++;
    }

    // ---- split owned keys: below-lo -> selk (self excluded), [lo,hi) -> candk ----
    int nbelow = 0, ecand = 0;
    #pragma unroll
    for (int t = 0; t < 4; t++) {
        unsigned long long kk = (t == 0) ? k0 : (t == 1) ? k1 : (t == 2) ? k2 : k3;
        unsigned hb = (unsigned)(kk >> 32);
        unsigned jj = (unsigned)kk;
        bool isb = (hb < loU) & (jj != (unsigned)i);
        bool isc = (hb >= loU) & (hb < hiU);
        unsigned long long mb = __ballot(isb);
        unsigned long long mc = __ballot(isc);
        if (isb) {
            int s = nbelow + lane_prefix(mb);
            if (s < 64) selk[w][s] = ((unsigned long long)hb << 32) | (unsigned)(jj * PP);
        }
        if (isc) {
            int s = ecand + lane_prefix(mc);
            if (s < 64) candk[w][s] = kk;
        }
        nbelow += (int)__popcll(mb);
        ecand  += (int)__popcll(mc);
    }
    if (ecand > 64) ecand = 64;
    __builtin_amdgcn_wave_barrier();

    // ---- rank candidates; append `need` smallest, skipping self ----
    const int need = K - cLo;                    // in [1, K]; ecand >= need
    unsigned long long mykey = ~0ull;
    if (lane < ecand) mykey = candk[w][lane];
    int mr = 0;
    for (int u = 0; u < ecand; u++) {            // ds_read_b64 broadcast, conflict-free
        unsigned long long ku = candk[w][u];
        mr += (ku < mykey) ? 1 : 0;
    }
    unsigned mj = (unsigned)mykey;
    bool ps = (lane < ecand) & (mr < need) & (mj != (unsigned)i);
    unsigned long long ms = __ballot(ps);
    if (ps) {
        int slot = nbelow + lane_prefix(ms);
        if (slot < 64)
            selk[w][slot] = (mykey & 0xFFFFFFFF00000000ull) | (unsigned)(mj * PP);
    }
    int nsel = nbelow + (int)__popcll(ms);       // expect K-1 = 39
    if (nsel > 64) nsel = 64;
    __builtin_amdgcn_wave_barrier();

    // ---- weights: hi word d2 -> exp(-d2) in place ----
    if (lane < nsel) {
        unsigned* su = (unsigned*)&selk[w][0];
        float d = __uint_as_float(su[2 * lane + 1]);
        su[2 * lane + 1] = __float_as_uint(__expf(-d));
    }
    __builtin_amdgcn_wave_barrier();

    // ---- weighted max / mean: lanes 0-21 do even m, lanes 32-53 odd m ----
    const int g = lane >> 5, c = lane & 31;
    const float* fbc = feats + (size_t)b * NN * PP + c;   // + jpp*4 via lshl_add_u64
    float mx = -INFINITY, sm = 0.f;
    if (c < PP) {
        #pragma unroll 4
        for (int m = g; m < nsel; m += 2) {
            unsigned long long e = selk[w][m];            // one b64 read: {weight, j*PP}
            float wt = __uint_as_float((unsigned)(e >> 32));
            float f  = fbc[(unsigned)e];
            float wf = wt * f;
            mx = fmaxf(mx, wf); sm += wf;
        }
    }
    float mx2 = __shfl_xor(mx, 32, 64);
    float sm2 = __shfl_xor(sm, 32, 64);
    mx = fmaxf(mx, mx2); sm += sm2;
    if (g == 0 && c < PP) {
        urow[w][c]      = mx;
        urow[w][PP + c] = sm / (float)(K - 1);
    }
    __builtin_amdgcn_wave_barrier();

    // ---- epilogue: out[q][o] = tanh(xwo + [max|mean] . Wo[64:,o]), lanes 0-41 ----
    if (lane < OO) {
        float a0 = xw, a1 = 0.f, a2 = 0.f, a3 = 0.f;
        const float* wo = Wo + FF * OO + lane;   // rows 64..107, coalesced across lanes
        #pragma unroll
        for (int k4 = 0; k4 < (2 * PP) / 4; k4++) {
            float4 u = *((const float4*)&urow[w][k4 * 4]);   // ds_read_b128 broadcast
            a0 = fmaf(u.x, wo[(k4 * 4 + 0) * OO], a0);
            a1 = fmaf(u.y, wo[(k4 * 4 + 1) * OO], a1);
            a2 = fmaf(u.z, wo[(k4 * 4 + 2) * OO], a2);
            a3 = fmaf(u.w, wo[(k4 * 4 + 3) * OO], a3);
        }
        float acc = (a0 + a1) + (a2 + a3);
        float a = acc < -12.f ? -12.f : (acc > 12.f ? 12.f : acc);
        float e2 = __expf(2.f * a);
        out[(size_t)q * OO + lane] = (e2 - 1.f) / (e2 + 1.f);
    }
}

extern "C" void kernel_launch(void* const* d_in, const int* in_sizes, int n_in,
                              void* d_out, int out_size, void* d_ws, size_t ws_size,
                              hipStream_t stream) {
    const float* x  = (const float*)d_in[0];
    const float* Ws = (const float*)d_in[1];
    const float* bs = (const float*)d_in[2];
    const float* Wf = (const float*)d_in[3];
    const float* bf = (const float*)d_in[4];
    const float* Wo = (const float*)d_in[5];
    const float* bo = (const float*)d_in[6];
    const int*   nn = (const int*)d_in[7];
    float* out = (float*)d_out;

    float* coords = (float*)d_ws;                              // 16*2048*4  = 512 KB
    float* feats  = coords + (size_t)BB * NN * SS;             // 16*2048*22 = 2.75 MB
    float* xwo    = feats  + (size_t)BB * NN * PP;             // 32768*42   = 5.5 MB

    prep_kernel<<<PREBLK + XWOBLK, 256, 0, stream>>>(x, Ws, bs, Wf, bf, Wo, bo, coords, feats, xwo);
    knn_out_kernel<<<(BB * NN) / 2, 128, 0, stream>>>(coords, feats, xwo, Wo, nn, out);
}

// Round 2
// 190.853 us; speedup vs baseline: 1.2064x; 1.2064x over previous
//
#include <hip/hip_runtime.h>
#include <math.h>

#define BB 16
#define NN 2048
#define FF 64
#define SS 4
#define PP 22
#define OO 42
#define FPDIM (FF + 2*PP)   // 108
#define NREG 32             // all 2048/64 d2 values kept in VGPRs per lane
#define PREBLK 128          // 128 blocks x 256 threads = one thread per row

__device__ __forceinline__ float readfirstlane_f32(float v) {
    // value-preserving wave-uniform broadcast (builtin is int->int; must pass bits!)
    return __uint_as_float((unsigned)__builtin_amdgcn_readfirstlane((int)__float_as_uint(v)));
}

// count of set bits below my lane (v_mbcnt_lo + v_mbcnt_hi, 2 VALU)
__device__ __forceinline__ int lane_prefix(unsigned long long m) {
    return __builtin_amdgcn_mbcnt_hi((unsigned)(m >> 32),
           __builtin_amdgcn_mbcnt_lo((unsigned)m, 0u));
}

// float wave sum via DPP chain (0-bits = 0.0f additive identity)
__device__ __forceinline__ float wave_fsum_dpp(float x) {
    float t;
    t = __uint_as_float((unsigned)__builtin_amdgcn_update_dpp(0, (int)__float_as_uint(x), 0x111, 0xf, 0xf, true)); x += t;
    t = __uint_as_float((unsigned)__builtin_amdgcn_update_dpp(0, (int)__float_as_uint(x), 0x112, 0xf, 0xf, true)); x += t;
    t = __uint_as_float((unsigned)__builtin_amdgcn_update_dpp(0, (int)__float_as_uint(x), 0x114, 0xf, 0xf, true)); x += t;
    t = __uint_as_float((unsigned)__builtin_amdgcn_update_dpp(0, (int)__float_as_uint(x), 0x118, 0xf, 0xf, true)); x += t;
    t = __uint_as_float((unsigned)__builtin_amdgcn_update_dpp(0, (int)__float_as_uint(x), 0x142, 0xa, 0xf, true)); x += t;
    t = __uint_as_float((unsigned)__builtin_amdgcn_update_dpp(0, (int)__float_as_uint(x), 0x143, 0xc, 0xf, true)); x += t;
    return __uint_as_float((unsigned)__builtin_amdgcn_readlane((int)__float_as_uint(x), 63));
}

// ---- Kernel 1: one thread per row computes coords[4], feats[22], xwo[42] ----
// R16: the old xwo grid portion (1 thread per (row,o-pair), 81 VMEM/thread x 688K
// threads = 55.7M VMEM ops ~ 91us of pure VMEM issue) is gone. Wo[:64] is staged in
// LDS (rows padded to 44 floats for 16B-aligned ds_read_b128 broadcasts) and each
// row-thread accumulates all 42 xwo outputs alongside coords/feats: x is loaded once.
__global__ __launch_bounds__(256) void prep_kernel(
    const float* __restrict__ x, const float* __restrict__ Ws, const float* __restrict__ bs,
    const float* __restrict__ Wf, const float* __restrict__ bf,
    const float* __restrict__ Wo, const float* __restrict__ bo,
    float* __restrict__ coords, float* __restrict__ feats, float* __restrict__ xwo)
{
    __shared__ float woLds[64 * 44];   // Wo rows 0..63, padded 42 -> 44 cols

    // cooperative stage: thread t -> row t>>2, quarter t&3 -> cols q*11 .. q*11+10
    {
        int wrow = threadIdx.x >> 2, quarter = threadIdx.x & 3;
        #pragma unroll
        for (int u = 0; u < 11; u++) {
            int c = quarter * 11 + u;                      // 0..43
            float v = (c < OO) ? Wo[wrow * OO + c] : 0.f;  // pad cols 42,43 with 0
            woLds[wrow * 44 + c] = v;
        }
    }
    __syncthreads();

    const int row = blockIdx.x * 256 + threadIdx.x;        // 0 .. 32767 exactly

    const float4* x4 = (const float4*)(x + (size_t)row * FF);
    float c0 = bs[0], c1 = bs[1], c2 = bs[2], c3 = bs[3];
    float f[PP];
    #pragma unroll
    for (int c = 0; c < PP; c++) f[c] = bf[c];
    float4 wa[11];
    #pragma unroll
    for (int c4 = 0; c4 < 10; c4++) wa[c4] = *((const float4*)(bo + c4 * 4));
    wa[10] = make_float4(bo[40], bo[41], 0.f, 0.f);        // avoid OOB read past bo[41]

    #pragma unroll
    for (int k4 = 0; k4 < FF / 4; k4++) {
        float4 xv = x4[k4];
        float xs[4] = {xv.x, xv.y, xv.z, xv.w};
        #pragma unroll
        for (int r = 0; r < 4; r++) {
            int k = k4 * 4 + r;
            float xk = xs[r];
            c0 = fmaf(xk, Ws[k * SS + 0], c0);
            c1 = fmaf(xk, Ws[k * SS + 1], c1);
            c2 = fmaf(xk, Ws[k * SS + 2], c2);
            c3 = fmaf(xk, Ws[k * SS + 3], c3);
            #pragma unroll
            for (int c = 0; c < PP; c++) f[c] = fmaf(xk, Wf[k * PP + c], f[c]);
            const float4* wrow = (const float4*)(woLds + k * 44);  // 16B-aligned
            #pragma unroll
            for (int c4 = 0; c4 < 11; c4++) {
                float4 wv = wrow[c4];                      // broadcast ds_read_b128
                wa[c4].x = fmaf(xk, wv.x, wa[c4].x);
                wa[c4].y = fmaf(xk, wv.y, wa[c4].y);
                wa[c4].z = fmaf(xk, wv.z, wa[c4].z);
                wa[c4].w = fmaf(xk, wv.w, wa[c4].w);
            }
        }
    }
    float4* cp = (float4*)(coords + (size_t)row * SS);
    *cp = make_float4(c0, c1, c2, c3);
    float* fo = feats + (size_t)row * PP;
    #pragma unroll
    for (int c = 0; c < PP; c++) fo[c] = f[c];
    float* xo = xwo + (size_t)row * OO;                    // row*168B: 8B-aligned
    #pragma unroll
    for (int c4 = 0; c4 < 10; c4++) {
        *((float2*)(xo + c4 * 4))     = make_float2(wa[c4].x, wa[c4].y);
        *((float2*)(xo + c4 * 4 + 2)) = make_float2(wa[c4].z, wa[c4].w);
    }
    *((float2*)(xo + 40)) = make_float2(wa[10].x, wa[10].y);
}

// ---- Kernel 2: wave-per-query kNN + aggregate + fused (neighbor-part) matvec/tanh ----
// Round-0 structure (proven 92us) with ONLY the counting mechanism changed:
// probe/bisect counts via __ballot + s_bcnt1 (scalar pipe) instead of v_addc chains +
// serial DPP-sum reductions; collect write-bases via per-r ballot+mbcnt instead of the
// packed DPP scan. Fast path, rank loop, exp, aggregation, epilogue are verbatim R14.
__global__ __launch_bounds__(128, 4) void knn_out_kernel(
    const float* __restrict__ coords, const float* __restrict__ feats,
    const float* __restrict__ xwo, const float* __restrict__ Wo,
    const int* __restrict__ nnbr, float* __restrict__ out)
{
    const int lane = threadIdx.x & 63;
    const int w    = threadIdx.x >> 6;
    const int q    = blockIdx.x * 2 + w;       // 0..32767
    const int b    = q >> 11;
    const int i    = q & (NN - 1);

    int K = *nnbr; K = K < 2 ? 2 : (K > 64 ? 64 : K);

    __shared__ int   isel[2][64];
    __shared__ float wsel[2][64];
    __shared__ unsigned long long candk[2][64];   // (d2bits<<32)|j packed keys
    __shared__ __align__(16) float urow[2][48];   // [max | mean], 44 used

    // prefetch the precomputed x-part of the output (overlaps the distance phase)
    float xw = 0.f;
    if (lane < OO) xw = xwo[(size_t)q * OO + lane];

    const float4* cb = (const float4*)(coords + (size_t)b * NN * SS);
    float4 qv = cb[i];
    const float qx = readfirstlane_f32(qv.x);
    const float qy = readfirstlane_f32(qv.y);
    const float qz = readfirstlane_f32(qv.z);
    const float qw = readfirstlane_f32(qv.w);

    // ---- distances: all 2048 kept in 32 VGPRs/lane; track per-lane min ----
    float d2r[NREG];
    float lmin = INFINITY;
    #pragma unroll 4
    for (int r = 0; r < NREG; r++) {
        float4 c = cb[r * 64 + lane];
        float d0 = qx - c.x, d1 = qy - c.y, d2 = qz - c.z, d3 = qw - c.w;
        float v = d0 * d0 + d1 * d1 + d2 * d2 + d3 * d3;
        d2r[r] = v;
        lmin = fminf(lmin, v);
    }

    // ---- first-probe estimator: mean of per-lane minima ~ K/N quantile ----
    float t0 = wave_fsum_dpp(lmin) * (1.0f / 64.0f);

    // ---- selection state: invariant cnt_lt(lo) < K <= cnt_lt(hi) ----
    unsigned loU = 0u, hiU = 0x7F800000u;   // [0, +inf)
    int cLo = 0, cHi = NN;
    float tPrev = t0; int cPrev = -1;

    // ---- quad-threshold opening probe (ballot counts, scalar-pipe accumulate) ----
    if (t0 > 1e-30f) {
        float t1 = t0 * 0.75f, t2 = t0 * 0.95f, t3 = t0 * 1.15f, t4 = t0 * 1.40f;
        int c1 = 0, c2 = 0, c3 = 0, c4 = 0;
        #pragma unroll
        for (int r = 0; r < NREG; r++) {
            float v = d2r[r];
            c1 += (int)__popcll(__ballot(v < t1));
            c2 += (int)__popcll(__ballot(v < t2));
            c3 += (int)__popcll(__ballot(v < t3));
            c4 += (int)__popcll(__ballot(v < t4));
        }
        if (c1 >= K)      { hiU = __float_as_uint(t1); cHi = c1; }
        else if (c2 >= K) { loU = __float_as_uint(t1); cLo = c1;
                            hiU = __float_as_uint(t2); cHi = c2; }
        else if (c3 >= K) { loU = __float_as_uint(t2); cLo = c2;
                            hiU = __float_as_uint(t3); cHi = c3; }
        else if (c4 >= K) { loU = __float_as_uint(t3); cLo = c3;
                            hiU = __float_as_uint(t4); cHi = c4; }
        else              { loU = __float_as_uint(t4); cLo = c4; }
        // anchor: nonzero count nearest K
        int bc = -1, bd = 0x7FFFFFFF; float bt = t0;
        int cs[4] = {c1, c2, c3, c4}; float ts[4] = {t1, t2, t3, t4};
        #pragma unroll
        for (int u = 0; u < 4; u++) {
            int d = cs[u] > K ? cs[u] - K : K - cs[u];
            if (cs[u] > 0 && d < bd) { bd = d; bc = cs[u]; bt = ts[u]; }
        }
        if (bc > 0) { tPrev = bt; cPrev = bc; }
        else        { tPrev = t4; cPrev = 0; }
    }

    // ---- dual-threshold bisection rounds (ballot counts) ----
    int probes = 0;
    while (cHi - cLo > 64 && hiU - loU > 1u && probes < 20) {
        unsigned tAU = 0u, tBU = 0u;
        bool fell = false;
        if (cPrev > 0) {
            float g = tPrev * __fsqrt_rn((float)K / (float)cPrev);
            tAU = __float_as_uint(g * 0.88f); tBU = __float_as_uint(g * 1.18f);
        } else if (cPrev == 0) {
            tAU = __float_as_uint(tPrev * 3.0f); tBU = __float_as_uint(tPrev * 9.0f);
        } else fell = true;
        unsigned span = hiU - loU;
        if (fell || !(tAU > loU && tAU < hiU)) tAU = loU + span / 3u;
        if (tAU <= loU) tAU = loU + 1u;
        if (tAU >= hiU) tAU = hiU - 1u;
        if (fell || !(tBU >= tAU && tBU < hiU)) tBU = tAU + (hiU - tAU) / 2u;
        if (tBU < tAU) tBU = tAU;
        if (tBU >= hiU) tBU = hiU - 1u;

        float tA = __uint_as_float(tAU), tB = __uint_as_float(tBU);
        int cA = 0, cB = 0;
        #pragma unroll
        for (int r = 0; r < NREG; r++) {
            float v = d2r[r];
            cA += (int)__popcll(__ballot(v < tA));
            cB += (int)__popcll(__ballot(v < tB));
        }

        if (cA >= K) { hiU = tAU; cHi = cA; }
        else {
            loU = tAU; cLo = cA;
            if (cB >= K) { hiU = tBU; cHi = cB; }
            else         { loU = tBU; cLo = cB; }
        }
        int dA = cA > K ? cA - K : K - cA;
        int dB = cB > K ? cB - K : K - cB;
        if (cA > 0 && dA <= dB) { tPrev = tA; cPrev = cA; }
        else                    { tPrev = tB; cPrev = cB; }
        probes++;
    }

    const float lo = __uint_as_float(loU);
    const float hi = __uint_as_float(hiU);
    const int  need = K - cLo;              // in [1, K]; window holds >= need values

    // ---- collect: per-r ballot + mbcnt write bases (below -> isel/wsel, window -> candk) ----
    int nbelow = 0, ecand = 0;
    #pragma unroll
    for (int r = 0; r < NREG; r++) {
        float v = d2r[r];
        int j = r * 64 + lane;
        bool isB = (v < lo) & (j != i);              // self d2=0 always < lo when lo>0
        bool isC = (v >= lo) & (v < hi);
        unsigned long long mB = __ballot(isB);
        unsigned long long mC = __ballot(isC);
        if (isB) {
            int s = nbelow + lane_prefix(mB);        // total below = cLo-1 <= K-1 <= 63
            isel[w][s] = j; wsel[w][s] = v;
        }
        if (isC) {
            int s = ecand + lane_prefix(mC);
            if (s < 64) candk[w][s] = ((unsigned long long)__float_as_uint(v) << 32) | (unsigned)j;
        }
        nbelow += (int)__popcll(mB);
        ecand  += (int)__popcll(mC);
    }
    if (ecand > 64) ecand = 64;
    __builtin_amdgcn_wave_barrier();

    // ---- append `need` smallest candidates (value,index), skipping self ----
    int nsel;
    if (ecand == need && loU > 0u) {
        // fast path: window exactly fills remaining slots; self is below lo (excluded)
        if (lane < ecand) {
            int slot = nbelow + lane;
            if (slot < 64) {
                unsigned long long k2 = candk[w][lane];
                isel[w][slot] = (int)(k2 & 0xFFFFFFFFull);
                wsel[w][slot] = __uint_as_float((unsigned)(k2 >> 32));
            }
        }
        nsel = nbelow + ecand;
        if (nsel > 64) nsel = 64;
    } else {
        unsigned long long mykey = ~0ull;
        if (lane < ecand) mykey = candk[w][lane];
        int mr = 0;
        for (int u = 0; u < ecand; u++) {        // ds_read_b64 broadcast, conflict-free
            unsigned long long k2 = candk[w][u];
            mr += (k2 < mykey) ? 1 : 0;
        }
        int mj = (int)(mykey & 0xFFFFFFFFull);
        bool ps = (lane < ecand) & (mr < need) & (mj != i);
        unsigned long long ms = __ballot(ps);
        if (ps) {
            int slot = nbelow + __popcll(ms & ((1ull << lane) - 1ull));
            if (slot < 64) { isel[w][slot] = mj; wsel[w][slot] = __uint_as_float((unsigned)(mykey >> 32)); }
        }
        nsel = nbelow + __popcll(ms);
        if (nsel > 64) nsel = 64;                // expect K-1 = 39
    }
    __builtin_amdgcn_wave_barrier();
    if (lane < nsel) wsel[w][lane] = __expf(-wsel[w][lane]);
    __builtin_amdgcn_wave_barrier();

    // ---- weighted max / mean: lanes 0-21 do even m, lanes 32-53 odd m ----
    const float* fb = feats + (size_t)b * NN * PP;
    int g = lane >> 5, c = lane & 31;
    float mx = -INFINITY, sm = 0.f;
    if (c < PP) {
        #pragma unroll 8
        for (int m = g; m < nsel; m += 2) {
            int j = isel[w][m]; float wt = wsel[w][m];
            float f = fb[(size_t)j * PP + c];
            float wf = wt * f;
            mx = fmaxf(mx, wf); sm += wf;
        }
    }
    float mx2 = __shfl_xor(mx, 32, 64);
    float sm2 = __shfl_xor(sm, 32, 64);
    mx = fmaxf(mx, mx2); sm += sm2;
    if (g == 0 && c < PP) {
        urow[w][c]      = mx;
        urow[w][PP + c] = sm / (float)(K - 1);
    }
    __builtin_amdgcn_wave_barrier();

    // ---- epilogue: out[q][o] = tanh(xwo + [max|mean] . Wo[64:,o]), lanes 0-41 ----
    if (lane < OO) {
        float a0 = xw, a1 = 0.f, a2 = 0.f, a3 = 0.f;
        const float* wo = Wo + FF * OO + lane;   // rows 64..107, coalesced across lanes
        #pragma unroll
        for (int k4 = 0; k4 < (2 * PP) / 4; k4++) {
            float4 u = *((const float4*)&urow[w][k4 * 4]);   // ds_read_b128 broadcast
            a0 = fmaf(u.x, wo[(k4 * 4 + 0) * OO], a0);
            a1 = fmaf(u.y, wo[(k4 * 4 + 1) * OO], a1);
            a2 = fmaf(u.z, wo[(k4 * 4 + 2) * OO], a2);
            a3 = fmaf(u.w, wo[(k4 * 4 + 3) * OO], a3);
        }
        float acc = (a0 + a1) + (a2 + a3);
        float a = acc < -12.f ? -12.f : (acc > 12.f ? 12.f : acc);
        float e2 = __expf(2.f * a);
        out[(size_t)q * OO + lane] = (e2 - 1.f) / (e2 + 1.f);
    }
}

extern "C" void kernel_launch(void* const* d_in, const int* in_sizes, int n_in,
                              void* d_out, int out_size, void* d_ws, size_t ws_size,
                              hipStream_t stream) {
    const float* x  = (const float*)d_in[0];
    const float* Ws = (const float*)d_in[1];
    const float* bs = (const float*)d_in[2];
    const float* Wf = (const float*)d_in[3];
    const float* bf = (const float*)d_in[4];
    const float* Wo = (const float*)d_in[5];
    const float* bo = (const float*)d_in[6];
    const int*   nn = (const int*)d_in[7];
    float* out = (float*)d_out;

    float* coords = (float*)d_ws;                              // 16*2048*4  = 512 KB
    float* feats  = coords + (size_t)BB * NN * SS;             // 16*2048*22 = 2.75 MB
    float* xwo    = feats  + (size_t)BB * NN * PP;             // 32768*42   = 5.5 MB

    prep_kernel<<<PREBLK, 256, 0, stream>>>(x, Ws, bs, Wf, bf, Wo, bo, coords, feats, xwo);
    knn_out_kernel<<<(BB * NN) / 2, 128, 0, stream>>>(coords, feats, xwo, Wo, nn, out);
}

// Round 3
// 173.265 us; speedup vs baseline: 1.3288x; 1.1015x over previous
//
#include <hip/hip_runtime.h>
#include <math.h>

#define BB 16
#define NN 2048
#define FF 64
#define SS 4
#define PP 22
#define OO 42
#define FPDIM (FF + 2*PP)   // 108
#define NREG 32             // all 2048/64 d2 values kept in VGPRs per lane
#define PREBLK 128          // blocks 0..127: coords/feats rows
#define XWOBLK 512          // blocks 128..639: xwo, 64 rows per block
#define WOPAD 68            // WoT row stride (16B-aligned, bank-spread)

__device__ __forceinline__ float readfirstlane_f32(float v) {
    // value-preserving wave-uniform broadcast (builtin is int->int; must pass bits!)
    return __uint_as_float((unsigned)__builtin_amdgcn_readfirstlane((int)__float_as_uint(v)));
}

// canonical GCN wave64 inclusive scan via DPP: row_shr 1/2/4/8 (bound_ctrl -> OOB reads 0),
// then row_bcast:15 into rows 1,3 and row_bcast:31 into rows 2,3. [R11/R12-validated]
__device__ __forceinline__ int wave_scan_dpp(int x) {
    x += __builtin_amdgcn_update_dpp(0, x, 0x111, 0xf, 0xf, true);  // row_shr:1
    x += __builtin_amdgcn_update_dpp(0, x, 0x112, 0xf, 0xf, true);  // row_shr:2
    x += __builtin_amdgcn_update_dpp(0, x, 0x114, 0xf, 0xf, true);  // row_shr:4
    x += __builtin_amdgcn_update_dpp(0, x, 0x118, 0xf, 0xf, true);  // row_shr:8
    x += __builtin_amdgcn_update_dpp(0, x, 0x142, 0xa, 0xf, true);  // row_bcast:15 -> rows 1,3
    x += __builtin_amdgcn_update_dpp(0, x, 0x143, 0xc, 0xf, true);  // row_bcast:31 -> rows 2,3
    return x;
}
__device__ __forceinline__ int wave_sum_dpp(int x) {
    return __builtin_amdgcn_readlane(wave_scan_dpp(x), 63);
}
// float wave sum: same chain in float domain (0-bits = 0.0f additive identity)
__device__ __forceinline__ float wave_fsum_dpp(float x) {
    float t;
    t = __uint_as_float((unsigned)__builtin_amdgcn_update_dpp(0, (int)__float_as_uint(x), 0x111, 0xf, 0xf, true)); x += t;
    t = __uint_as_float((unsigned)__builtin_amdgcn_update_dpp(0, (int)__float_as_uint(x), 0x112, 0xf, 0xf, true)); x += t;
    t = __uint_as_float((unsigned)__builtin_amdgcn_update_dpp(0, (int)__float_as_uint(x), 0x114, 0xf, 0xf, true)); x += t;
    t = __uint_as_float((unsigned)__builtin_amdgcn_update_dpp(0, (int)__float_as_uint(x), 0x118, 0xf, 0xf, true)); x += t;
    t = __uint_as_float((unsigned)__builtin_amdgcn_update_dpp(0, (int)__float_as_uint(x), 0x142, 0xa, 0xf, true)); x += t;
    t = __uint_as_float((unsigned)__builtin_amdgcn_update_dpp(0, (int)__float_as_uint(x), 0x143, 0xc, 0xf, true)); x += t;
    return __uint_as_float((unsigned)__builtin_amdgcn_readlane((int)__float_as_uint(x), 63));
}

// ---- Kernel 1: blocks 0..127 -> coords/feats (row/thread); 128..639 -> xwo tiles ----
// R17 xwo path: wave-per-64-rows, cols split across the block's 4 waves. Wo[:64] is
// staged TRANSPOSED in LDS (stride 68: 16B-aligned rows, bank-spread) so the inner
// loop reads are wave-UNIFORM ds_read_b128 broadcasts (no per-lane gather, no VMEM).
// Outputs buffered in LDS [64][42] then stored as 672 coalesced float4 per block
// (the row-major [42] layout is scatter-hostile for direct per-lane stores).
__global__ __launch_bounds__(256) void prep_kernel(
    const float* __restrict__ x, const float* __restrict__ Ws, const float* __restrict__ bs,
    const float* __restrict__ Wf, const float* __restrict__ bf,
    const float* __restrict__ Wo, const float* __restrict__ bo,
    float* __restrict__ coords, float* __restrict__ feats, float* __restrict__ xwo)
{
    __shared__ float woT[OO * WOPAD];   // 42 x 68 floats = 11.4 KB (xwo blocks only)
    __shared__ float obuf[64 * OO];     // 64 x 42 floats = 10.5 KB block output tile

    if (blockIdx.x >= PREBLK) {
        const int xblk = blockIdx.x - PREBLK;       // 0..511
        const int r0   = xblk * 64;
        const int lane = threadIdx.x & 63;
        const int wv   = threadIdx.x >> 6;          // 0..3

        // stage Wo[0:64][0:42] transposed: coalesced global reads, padded LDS writes
        for (int idx = threadIdx.x; idx < 64 * OO; idx += 256) {
            int k = idx / OO;                       // compile-time magic-mul
            int o = idx - k * OO;
            woT[o * WOPAD + k] = Wo[idx];
        }
        __syncthreads();

        // x row -> 16 float4 in VGPRs
        const int row = r0 + lane;
        const float4* xr = (const float4*)(x + (size_t)row * FF);
        float4 xv[16];
        #pragma unroll
        for (int k4 = 0; k4 < 16; k4++) xv[k4] = xr[k4];

        const int cbase = wv * 11;
        const int nc = (wv == 3) ? 9 : 11;          // cols 33..41 for wave 3
        #pragma unroll
        for (int u = 0; u < 11; u++) {
            if (u < nc) {                           // wave-uniform guard
                int o = cbase + u;
                float a0 = bo[o], a1 = 0.f, a2 = 0.f, a3 = 0.f;
                const float4* wt = (const float4*)(woT + o * WOPAD);
                #pragma unroll
                for (int k4 = 0; k4 < 16; k4++) {
                    float4 wv4 = wt[k4];            // uniform-addr ds_read_b128 broadcast
                    a0 = fmaf(xv[k4].x, wv4.x, a0);
                    a1 = fmaf(xv[k4].y, wv4.y, a1);
                    a2 = fmaf(xv[k4].z, wv4.z, a2);
                    a3 = fmaf(xv[k4].w, wv4.w, a3);
                }
                obuf[lane * OO + o] = (a0 + a1) + (a2 + a3);   // 4-way bank alias, 11 writes
            }
        }
        __syncthreads();

        // block tile rows r0..r0+63 are CONTIGUOUS in xwo: 2688 floats, 16B-aligned
        const float4* ob4 = (const float4*)obuf;
        float4* gout = (float4*)(xwo + (size_t)r0 * OO);
        for (int t = threadIdx.x; t < (64 * OO) / 4; t += 256) gout[t] = ob4[t];
        return;
    }

    // ---- coords = x@W_s + b_s ; feats = x@W_f + b_f (R0-proven path) ----
    int row = blockIdx.x * 256 + threadIdx.x;   // 0 .. B*N-1
    if (row >= BB * NN) return;

    const float4* x4 = (const float4*)(x + (size_t)row * FF);
    float c0 = bs[0], c1 = bs[1], c2 = bs[2], c3 = bs[3];
    float f[PP];
    #pragma unroll
    for (int c = 0; c < PP; c++) f[c] = bf[c];

    #pragma unroll
    for (int k4 = 0; k4 < FF / 4; k4++) {
        float4 xv = x4[k4];
        float xs[4] = {xv.x, xv.y, xv.z, xv.w};
        #pragma unroll
        for (int r = 0; r < 4; r++) {
            int k = k4 * 4 + r;
            float xk = xs[r];
            c0 = fmaf(xk, Ws[k * SS + 0], c0);
            c1 = fmaf(xk, Ws[k * SS + 1], c1);
            c2 = fmaf(xk, Ws[k * SS + 2], c2);
            c3 = fmaf(xk, Ws[k * SS + 3], c3);
            #pragma unroll
            for (int c = 0; c < PP; c++) f[c] = fmaf(xk, Wf[k * PP + c], f[c]);
        }
    }
    float4* cp = (float4*)(coords + (size_t)row * SS);
    *cp = make_float4(c0, c1, c2, c3);
    float* fo = feats + (size_t)row * PP;
    #pragma unroll
    for (int c = 0; c < PP; c++) fo[c] = f[c];
}

// ---- Kernel 2: wave-per-query kNN + aggregate + fused (neighbor-part) matvec/tanh ----
// EXACT round-0 version (92us proven: VALUBusy 74%, occ 75%, VGPR 32). R15/R16's
// ballot/popcount counting regressed it: s_bcnt1/s_add land on the per-CU-shared
// scalar unit (1 instr/cyc/CU vs 2 VALU wave-ops/cyc/CU) -> issue-bound on SALU.
__global__ __launch_bounds__(128, 4) void knn_out_kernel(
    const float* __restrict__ coords, const float* __restrict__ feats,
    const float* __restrict__ xwo, const float* __restrict__ Wo,
    const int* __restrict__ nnbr, float* __restrict__ out)
{
    const int lane = threadIdx.x & 63;
    const int w    = threadIdx.x >> 6;
    const int q    = blockIdx.x * 2 + w;       // 0..32767
    const int b    = q >> 11;
    const int i    = q & (NN - 1);

    int K = *nnbr; K = K < 2 ? 2 : (K > 64 ? 64 : K);

    __shared__ int   isel[2][64];
    __shared__ float wsel[2][64];
    __shared__ unsigned long long candk[2][64];   // (d2bits<<32)|j packed keys
    __shared__ __align__(16) float urow[2][48];   // [max | mean], 44 used

    // prefetch the precomputed x-part of the output (overlaps the distance phase)
    float xw = 0.f;
    if (lane < OO) xw = xwo[(size_t)q * OO + lane];

    const float4* cb = (const float4*)(coords + (size_t)b * NN * SS);
    float4 qv = cb[i];
    const float qx = readfirstlane_f32(qv.x);
    const float qy = readfirstlane_f32(qv.y);
    const float qz = readfirstlane_f32(qv.z);
    const float qw = readfirstlane_f32(qv.w);

    // ---- distances: all 2048 kept in 32 VGPRs/lane; track per-lane min ----
    float d2r[NREG];
    float lmin = INFINITY;
    #pragma unroll 4
    for (int r = 0; r < NREG; r++) {
        float4 c = cb[r * 64 + lane];
        float d0 = qx - c.x, d1 = qy - c.y, d2 = qz - c.z, d3 = qw - c.w;
        float v = d0 * d0 + d1 * d1 + d2 * d2 + d3 * d3;
        d2r[r] = v;
        lmin = fminf(lmin, v);
    }

    // ---- first-probe estimator: mean of per-lane minima ~ K/N quantile (DPP sum) ----
    float t0 = wave_fsum_dpp(lmin) * (1.0f / 64.0f);

    // ---- selection state: invariant cnt_lt(lo) < K <= cnt_lt(hi) ----
    unsigned loU = 0u, hiU = 0x7F800000u;   // [0, +inf)
    int cLo = 0, cHi = NN;
    int laneLo = 0, laneHi = NREG;          // per-lane counts at loU / hiU
    float tPrev = t0; int cPrev = -1;

    // ---- quad-threshold opening probe (two packed DPP sums, latency-overlapped) ----
    if (t0 > 1e-30f) {
        float t1 = t0 * 0.75f, t2 = t0 * 0.95f, t3 = t0 * 1.15f, t4 = t0 * 1.40f;
        int l1 = 0, l2 = 0, l3 = 0, l4 = 0;
        #pragma unroll
        for (int r = 0; r < NREG; r++) {
            float v = d2r[r];
            l1 += (v < t1) ? 1 : 0;
            l2 += (v < t2) ? 1 : 0;
            l3 += (v < t3) ? 1 : 0;
            l4 += (v < t4) ? 1 : 0;
        }
        int s12 = wave_sum_dpp(l1 | (l2 << 16));
        int s34 = wave_sum_dpp(l3 | (l4 << 16));
        int c1 = s12 & 0xFFFF, c2 = s12 >> 16, c3 = s34 & 0xFFFF, c4 = s34 >> 16;
        if (c1 >= K)      { hiU = __float_as_uint(t1); cHi = c1; laneHi = l1; }
        else if (c2 >= K) { loU = __float_as_uint(t1); cLo = c1; laneLo = l1;
                            hiU = __float_as_uint(t2); cHi = c2; laneHi = l2; }
        else if (c3 >= K) { loU = __float_as_uint(t2); cLo = c2; laneLo = l2;
                            hiU = __float_as_uint(t3); cHi = c3; laneHi = l3; }
        else if (c4 >= K) { loU = __float_as_uint(t3); cLo = c3; laneLo = l3;
                            hiU = __float_as_uint(t4); cHi = c4; laneHi = l4; }
        else              { loU = __float_as_uint(t4); cLo = c4; laneLo = l4; }
        // anchor: nonzero count nearest K
        int bc = -1, bd = 0x7FFFFFFF; float bt = t0;
        int cs[4] = {c1, c2, c3, c4}; float ts[4] = {t1, t2, t3, t4};
        #pragma unroll
        for (int u = 0; u < 4; u++) {
            int d = cs[u] > K ? cs[u] - K : K - cs[u];
            if (cs[u] > 0 && d < bd) { bd = d; bc = cs[u]; bt = ts[u]; }
        }
        if (bc > 0) { tPrev = bt; cPrev = bc; }
        else        { tPrev = t4; cPrev = 0; }
    }

    // ---- dual-threshold bisection rounds (DPP sums) ----
    int probes = 0;
    while (cHi - cLo > 64 && hiU - loU > 1u && probes < 20) {
        unsigned tAU = 0u, tBU = 0u;
        bool fell = false;
        if (cPrev > 0) {
            float g = tPrev * __fsqrt_rn((float)K / (float)cPrev);
            tAU = __float_as_uint(g * 0.88f); tBU = __float_as_uint(g * 1.18f);
        } else if (cPrev == 0) {
            tAU = __float_as_uint(tPrev * 3.0f); tBU = __float_as_uint(tPrev * 9.0f);
        } else fell = true;
        unsigned span = hiU - loU;
        if (fell || !(tAU > loU && tAU < hiU)) tAU = loU + span / 3u;
        if (tAU <= loU) tAU = loU + 1u;
        if (tAU >= hiU) tAU = hiU - 1u;
        if (fell || !(tBU >= tAU && tBU < hiU)) tBU = tAU + (hiU - tAU) / 2u;
        if (tBU < tAU) tBU = tAU;
        if (tBU >= hiU) tBU = hiU - 1u;

        float tA = __uint_as_float(tAU), tB = __uint_as_float(tBU);
        int clA = 0, clB = 0;
        #pragma unroll
        for (int r = 0; r < NREG; r++) {
            clA += (d2r[r] < tA) ? 1 : 0;
            clB += (d2r[r] < tB) ? 1 : 0;
        }
        int tot = wave_sum_dpp(clA | (clB << 16));   // sums fit 16 bits each (<= 2048)
        int cA = tot & 0xFFFF, cB = tot >> 16;

        if (cA >= K) { hiU = tAU; cHi = cA; laneHi = clA; }
        else {
            loU = tAU; cLo = cA; laneLo = clA;
            if (cB >= K) { hiU = tBU; cHi = cB; laneHi = clB; }
            else         { loU = tBU; cLo = cB; laneLo = clB; }
        }
        int dA = cA > K ? cA - K : K - cA;
        int dB = cB > K ? cB - K : K - cB;
        if (cA > 0 && dA <= dB) { tPrev = tA; cPrev = cA; }
        else                    { tPrev = tB; cPrev = cB; }
        probes++;
    }

    const float lo = __uint_as_float(loU);
    const float hi = __uint_as_float(hiU);
    const int  need = K - cLo;              // in [1, K]; window holds >= need values

    // ---- collect: counts known per lane; DPP scan -> sequential writes ----
    int c1c = laneLo;                       // # of my elems with v < lo (minus self if below)
    int c2c = laneHi - laneLo;              // # of my elems in [lo, hi)
    if (lane == (i & 63) && loU > 0u) c1c -= 1;  // self d2=0 < lo counted in laneLo
    int pk = c1c | (c2c << 16);
    int inc = wave_scan_dpp(pk);
    int excl = inc - pk;
    int tot  = __builtin_amdgcn_readlane(inc, 63);
    int b1 = excl & 0xFFFF;            // per-lane write base, below-window
    int b2 = excl >> 16;               // per-lane write base, candidates
    const int nbelow = tot & 0xFFFF;   // <= K-1
    int ecand = tot >> 16; if (ecand > 64) ecand = 64;
    #pragma unroll
    for (int r = 0; r < NREG; r++) {
        float v = d2r[r];
        int j = r * 64 + lane;
        if ((v < lo) & (j != i)) { isel[w][b1] = j; wsel[w][b1] = v; b1++; }
        else if ((v >= lo) & (v < hi)) { if (b2 < 64) candk[w][b2] = ((unsigned long long)__float_as_uint(v) << 32) | (unsigned)j; b2++; }
    }
    __builtin_amdgcn_wave_barrier();

    // ---- append `need` smallest candidates (value,index), skipping self ----
    int nsel;
    if (ecand == need && loU > 0u) {
        // fast path: window exactly fills remaining slots; self is below lo (excluded)
        if (lane < ecand) {
            int slot = nbelow + lane;
            if (slot < 64) {
                unsigned long long k2 = candk[w][lane];
                isel[w][slot] = (int)(k2 & 0xFFFFFFFFull);
                wsel[w][slot] = __uint_as_float((unsigned)(k2 >> 32));
            }
        }
        nsel = nbelow + ecand;
        if (nsel > 64) nsel = 64;
    } else {
        unsigned long long mykey = ~0ull;
        if (lane < ecand) mykey = candk[w][lane];
        int mr = 0;
        for (int u = 0; u < ecand; u++) {        // ds_read_b64 broadcast, conflict-free
            unsigned long long k2 = candk[w][u];
            mr += (k2 < mykey) ? 1 : 0;
        }
        int mj = (int)(mykey & 0xFFFFFFFFull);
        bool ps = (lane < ecand) & (mr < need) & (mj != i);
        unsigned long long ms = __ballot(ps);
        if (ps) {
            int slot = nbelow + __popcll(ms & ((1ull << lane) - 1ull));
            if (slot < 64) { isel[w][slot] = mj; wsel[w][slot] = __uint_as_float((unsigned)(mykey >> 32)); }
        }
        nsel = nbelow + __popcll(ms);
        if (nsel > 64) nsel = 64;                // expect K-1 = 39
    }
    __builtin_amdgcn_wave_barrier();
    if (lane < nsel) wsel[w][lane] = __expf(-wsel[w][lane]);
    __builtin_amdgcn_wave_barrier();

    // ---- weighted max / mean: lanes 0-21 do even m, lanes 32-53 odd m ----
    const float* fb = feats + (size_t)b * NN * PP;
    int g = lane >> 5, c = lane & 31;
    float mx = -INFINITY, sm = 0.f;
    if (c < PP) {
        #pragma unroll 8
        for (int m = g; m < nsel; m += 2) {
            int j = isel[w][m]; float wt = wsel[w][m];
            float f = fb[(size_t)j * PP + c];
            float wf = wt * f;
            mx = fmaxf(mx, wf); sm += wf;
        }
    }
    float mx2 = __shfl_xor(mx, 32, 64);
    float sm2 = __shfl_xor(sm, 32, 64);
    mx = fmaxf(mx, mx2); sm += sm2;
    if (g == 0 && c < PP) {
        urow[w][c]      = mx;
        urow[w][PP + c] = sm / (float)(K - 1);
    }
    __builtin_amdgcn_wave_barrier();

    // ---- epilogue: out[q][o] = tanh(xwo + [max|mean] . Wo[64:,o]), lanes 0-41 ----
    if (lane < OO) {
        float a0 = xw, a1 = 0.f, a2 = 0.f, a3 = 0.f;
        const float* wo = Wo + FF * OO + lane;   // rows 64..107, coalesced across lanes
        #pragma unroll
        for (int k4 = 0; k4 < (2 * PP) / 4; k4++) {
            float4 u = *((const float4*)&urow[w][k4 * 4]);   // ds_read_b128 broadcast
            a0 = fmaf(u.x, wo[(k4 * 4 + 0) * OO], a0);
            a1 = fmaf(u.y, wo[(k4 * 4 + 1) * OO], a1);
            a2 = fmaf(u.z, wo[(k4 * 4 + 2) * OO], a2);
            a3 = fmaf(u.w, wo[(k4 * 4 + 3) * OO], a3);
        }
        float acc = (a0 + a1) + (a2 + a3);
        float a = acc < -12.f ? -12.f : (acc > 12.f ? 12.f : acc);
        float e2 = __expf(2.f * a);
        out[(size_t)q * OO + lane] = (e2 - 1.f) / (e2 + 1.f);
    }
}

extern "C" void kernel_launch(void* const* d_in, const int* in_sizes, int n_in,
                              void* d_out, int out_size, void* d_ws, size_t ws_size,
                              hipStream_t stream) {
    const float* x  = (const float*)d_in[0];
    const float* Ws = (const float*)d_in[1];
    const float* bs = (const float*)d_in[2];
    const float* Wf = (const float*)d_in[3];
    const float* bf = (const float*)d_in[4];
    const float* Wo = (const float*)d_in[5];
    const float* bo = (const float*)d_in[6];
    const int*   nn = (const int*)d_in[7];
    float* out = (float*)d_out;

    float* coords = (float*)d_ws;                              // 16*2048*4  = 512 KB
    float* feats  = coords + (size_t)BB * NN * SS;             // 16*2048*22 = 2.75 MB
    float* xwo    = feats  + (size_t)BB * NN * PP;             // 32768*42   = 5.5 MB

    prep_kernel<<<PREBLK + XWOBLK, 256, 0, stream>>>(x, Ws, bs, Wf, bf, Wo, bo, coords, feats, xwo);
    knn_out_kernel<<<(BB * NN) / 2, 128, 0, stream>>>(coords, feats, xwo, Wo, nn, out);
}

// Round 4
// 171.318 us; speedup vs baseline: 1.3439x; 1.0114x over previous
//
#include <hip/hip_runtime.h>
#include <math.h>

#define BB 16
#define NN 2048
#define FF 64
#define SS 4
#define PP 22
#define OO 42
#define FPDIM (FF + 2*PP)   // 108
#define NREG 32             // all 2048/64 d2 values kept in VGPRs per lane
#define XBLK 512            // prep blocks: 64 rows each, 512*64 = 32768 rows
#define WST 68              // LDS row stride (floats): 16B-aligned, non-mult-of-32

__device__ __forceinline__ float readfirstlane_f32(float v) {
    // value-preserving wave-uniform broadcast (builtin is int->int; must pass bits!)
    return __uint_as_float((unsigned)__builtin_amdgcn_readfirstlane((int)__float_as_uint(v)));
}

// canonical GCN wave64 inclusive scan via DPP: row_shr 1/2/4/8 (bound_ctrl -> OOB reads 0),
// then row_bcast:15 into rows 1,3 and row_bcast:31 into rows 2,3. [R11/R12-validated]
__device__ __forceinline__ int wave_scan_dpp(int x) {
    x += __builtin_amdgcn_update_dpp(0, x, 0x111, 0xf, 0xf, true);  // row_shr:1
    x += __builtin_amdgcn_update_dpp(0, x, 0x112, 0xf, 0xf, true);  // row_shr:2
    x += __builtin_amdgcn_update_dpp(0, x, 0x114, 0xf, 0xf, true);  // row_shr:4
    x += __builtin_amdgcn_update_dpp(0, x, 0x118, 0xf, 0xf, true);  // row_shr:8
    x += __builtin_amdgcn_update_dpp(0, x, 0x142, 0xa, 0xf, true);  // row_bcast:15 -> rows 1,3
    x += __builtin_amdgcn_update_dpp(0, x, 0x143, 0xc, 0xf, true);  // row_bcast:31 -> rows 2,3
    return x;
}
__device__ __forceinline__ int wave_sum_dpp(int x) {
    return __builtin_amdgcn_readlane(wave_scan_dpp(x), 63);
}
// float wave sum: same chain in float domain (0-bits = 0.0f additive identity)
__device__ __forceinline__ float wave_fsum_dpp(float x) {
    float t;
    t = __uint_as_float((unsigned)__builtin_amdgcn_update_dpp(0, (int)__float_as_uint(x), 0x111, 0xf, 0xf, true)); x += t;
    t = __uint_as_float((unsigned)__builtin_amdgcn_update_dpp(0, (int)__float_as_uint(x), 0x112, 0xf, 0xf, true)); x += t;
    t = __uint_as_float((unsigned)__builtin_amdgcn_update_dpp(0, (int)__float_as_uint(x), 0x114, 0xf, 0xf, true)); x += t;
    t = __uint_as_float((unsigned)__builtin_amdgcn_update_dpp(0, (int)__float_as_uint(x), 0x118, 0xf, 0xf, true)); x += t;
    t = __uint_as_float((unsigned)__builtin_amdgcn_update_dpp(0, (int)__float_as_uint(x), 0x142, 0xa, 0xf, true)); x += t;
    t = __uint_as_float((unsigned)__builtin_amdgcn_update_dpp(0, (int)__float_as_uint(x), 0x143, 0xc, 0xf, true)); x += t;
    return __uint_as_float((unsigned)__builtin_amdgcn_readlane((int)__float_as_uint(x), 63));
}

// ---- Kernel 1 (R18): unified 68-col GEMM, wave-per-64-rows, LDS-staged weights ----
// The old row-per-thread coords/feats path (128 blocks, 1 wave/SIMD on half the chip)
// was LATENCY-bound: 64x26 fully-unrolled fma with 26 live accumulators left the
// compiler no registers to pipeline the 1664 weight loads -> ~112 cyc stall per load
// ~ 78us. Now: W = [Ws|Wf|Wo[:64]] transposed in LDS, 4 waves x 17 cols per block,
// wave-uniform ds_read_b128 broadcasts, 512 blocks (2/CU, 8 waves/CU) for TLP.
__global__ __launch_bounds__(256) void prep_kernel(
    const float* __restrict__ x, const float* __restrict__ Ws, const float* __restrict__ bs,
    const float* __restrict__ Wf, const float* __restrict__ bf,
    const float* __restrict__ Wo, const float* __restrict__ bo,
    float* __restrict__ coords, float* __restrict__ feats, float* __restrict__ xwo)
{
    __shared__ float wT[68 * WST];      // [o][k] transposed weights   (18.5 KB)
    __shared__ float obufT[68 * WST];   // [o][row-lane] output tile   (18.5 KB)
    __shared__ float bvec[68];

    const int lane = threadIdx.x & 63;
    const int wv   = threadIdx.x >> 6;          // 0..3
    const int r0   = blockIdx.x * 64;

    // x tile first: 16 independent coalesced-per-row loads, in flight during staging
    const float4* xr = (const float4*)(x + (size_t)(r0 + lane) * FF);
    float4 xv[16];
    #pragma unroll
    for (int k4 = 0; k4 < 16; k4++) xv[k4] = xr[k4];

    // stage weights transposed: coalesced global reads, scattered LDS writes
    {
        int t = threadIdx.x;                    // Ws: 64x4 = 256 elems, one each
        int k = t >> 2, s = t & 3;
        wT[s * WST + k] = Ws[t];
    }
    for (int t = threadIdx.x; t < 64 * PP; t += 256) {       // Wf: 1408
        int k = t / PP, c = t - k * PP;
        wT[(4 + c) * WST + k] = Wf[t];
    }
    for (int t = threadIdx.x; t < 64 * OO; t += 256) {       // Wo rows 0..63: 2688
        int k = t / OO, o = t - k * OO;
        wT[(26 + o) * WST + k] = Wo[t];
    }
    if (threadIdx.x < 68) {
        int o = threadIdx.x;
        bvec[o] = o < 4 ? bs[o] : (o < 26 ? bf[o - 4] : bo[o - 26]);
    }
    __syncthreads();

    // compute: wave wv owns cols [17wv, 17wv+17); lane <-> row
    for (int u = 0; u < 17; u++) {
        int o = wv * 17 + u;
        float a0 = bvec[o], a1 = 0.f, a2 = 0.f, a3 = 0.f;
        const float4* wrow = (const float4*)(wT + o * WST);  // 272B stride: 16B-aligned
        #pragma unroll
        for (int k4 = 0; k4 < 16; k4++) {
            float4 w4 = wrow[k4];               // wave-uniform ds_read_b128 broadcast
            a0 = fmaf(xv[k4].x, w4.x, a0);
            a1 = fmaf(xv[k4].y, w4.y, a1);
            a2 = fmaf(xv[k4].z, w4.z, a2);
            a3 = fmaf(xv[k4].w, w4.w, a3);
        }
        obufT[o * WST + lane] = (a0 + a1) + (a2 + a3);       // consecutive lanes: no conflict
    }
    __syncthreads();

    // ---- coalesced stores from the LDS tile ----
    // coords: rows r0..r0+63, 4 floats each (threads 0..63, one float4 apiece)
    if (threadIdx.x < 64) {
        int r = threadIdx.x;
        float4 cv = make_float4(obufT[0 * WST + r], obufT[1 * WST + r],
                                obufT[2 * WST + r], obufT[3 * WST + r]);
        *((float4*)(coords + (size_t)(r0 + r) * SS)) = cv;
    }
    // feats: 64x22 floats = 704 float2; linear 2t = row*22 + 2*c2
    for (int t = threadIdx.x; t < 32 * PP; t += 256) {
        int row = t / 11, c2 = t - row * 11;
        float2 v = make_float2(obufT[(4 + 2 * c2) * WST + row],
                               obufT[(4 + 2 * c2 + 1) * WST + row]);
        *((float2*)(feats + (size_t)r0 * PP + 2 * t)) = v;
    }
    // xwo: 64x42 floats = 1344 float2; linear 2t = row*42 + 2*c2
    for (int t = threadIdx.x; t < 32 * OO; t += 256) {
        int row = t / 21, c2 = t - row * 21;
        float2 v = make_float2(obufT[(26 + 2 * c2) * WST + row],
                               obufT[(26 + 2 * c2 + 1) * WST + row]);
        *((float2*)(xwo + (size_t)r0 * OO + 2 * t)) = v;
    }
}

// ---- Kernel 2: wave-per-query kNN + aggregate + fused (neighbor-part) matvec/tanh ----
// EXACT round-0 version (91.6us re-proven in R3: VALUBusy 74%, occ 75%, VGPR 32).
__global__ __launch_bounds__(128, 4) void knn_out_kernel(
    const float* __restrict__ coords, const float* __restrict__ feats,
    const float* __restrict__ xwo, const float* __restrict__ Wo,
    const int* __restrict__ nnbr, float* __restrict__ out)
{
    const int lane = threadIdx.x & 63;
    const int w    = threadIdx.x >> 6;
    const int q    = blockIdx.x * 2 + w;       // 0..32767
    const int b    = q >> 11;
    const int i    = q & (NN - 1);

    int K = *nnbr; K = K < 2 ? 2 : (K > 64 ? 64 : K);

    __shared__ int   isel[2][64];
    __shared__ float wsel[2][64];
    __shared__ unsigned long long candk[2][64];   // (d2bits<<32)|j packed keys
    __shared__ __align__(16) float urow[2][48];   // [max | mean], 44 used

    // prefetch the precomputed x-part of the output (overlaps the distance phase)
    float xw = 0.f;
    if (lane < OO) xw = xwo[(size_t)q * OO + lane];

    const float4* cb = (const float4*)(coords + (size_t)b * NN * SS);
    float4 qv = cb[i];
    const float qx = readfirstlane_f32(qv.x);
    const float qy = readfirstlane_f32(qv.y);
    const float qz = readfirstlane_f32(qv.z);
    const float qw = readfirstlane_f32(qv.w);

    // ---- distances: all 2048 kept in 32 VGPRs/lane; track per-lane min ----
    float d2r[NREG];
    float lmin = INFINITY;
    #pragma unroll 4
    for (int r = 0; r < NREG; r++) {
        float4 c = cb[r * 64 + lane];
        float d0 = qx - c.x, d1 = qy - c.y, d2 = qz - c.z, d3 = qw - c.w;
        float v = d0 * d0 + d1 * d1 + d2 * d2 + d3 * d3;
        d2r[r] = v;
        lmin = fminf(lmin, v);
    }

    // ---- first-probe estimator: mean of per-lane minima ~ K/N quantile (DPP sum) ----
    float t0 = wave_fsum_dpp(lmin) * (1.0f / 64.0f);

    // ---- selection state: invariant cnt_lt(lo) < K <= cnt_lt(hi) ----
    unsigned loU = 0u, hiU = 0x7F800000u;   // [0, +inf)
    int cLo = 0, cHi = NN;
    int laneLo = 0, laneHi = NREG;          // per-lane counts at loU / hiU
    float tPrev = t0; int cPrev = -1;

    // ---- quad-threshold opening probe (two packed DPP sums, latency-overlapped) ----
    if (t0 > 1e-30f) {
        float t1 = t0 * 0.75f, t2 = t0 * 0.95f, t3 = t0 * 1.15f, t4 = t0 * 1.40f;
        int l1 = 0, l2 = 0, l3 = 0, l4 = 0;
        #pragma unroll
        for (int r = 0; r < NREG; r++) {
            float v = d2r[r];
            l1 += (v < t1) ? 1 : 0;
            l2 += (v < t2) ? 1 : 0;
            l3 += (v < t3) ? 1 : 0;
            l4 += (v < t4) ? 1 : 0;
        }
        int s12 = wave_sum_dpp(l1 | (l2 << 16));
        int s34 = wave_sum_dpp(l3 | (l4 << 16));
        int c1 = s12 & 0xFFFF, c2 = s12 >> 16, c3 = s34 & 0xFFFF, c4 = s34 >> 16;
        if (c1 >= K)      { hiU = __float_as_uint(t1); cHi = c1; laneHi = l1; }
        else if (c2 >= K) { loU = __float_as_uint(t1); cLo = c1; laneLo = l1;
                            hiU = __float_as_uint(t2); cHi = c2; laneHi = l2; }
        else if (c3 >= K) { loU = __float_as_uint(t2); cLo = c2; laneLo = l2;
                            hiU = __float_as_uint(t3); cHi = c3; laneHi = l3; }
        else if (c4 >= K) { loU = __float_as_uint(t3); cLo = c3; laneLo = l3;
                            hiU = __float_as_uint(t4); cHi = c4; laneHi = l4; }
        else              { loU = __float_as_uint(t4); cLo = c4; laneLo = l4; }
        // anchor: nonzero count nearest K
        int bc = -1, bd = 0x7FFFFFFF; float bt = t0;
        int cs[4] = {c1, c2, c3, c4}; float ts[4] = {t1, t2, t3, t4};
        #pragma unroll
        for (int u = 0; u < 4; u++) {
            int d = cs[u] > K ? cs[u] - K : K - cs[u];
            if (cs[u] > 0 && d < bd) { bd = d; bc = cs[u]; bt = ts[u]; }
        }
        if (bc > 0) { tPrev = bt; cPrev = bc; }
        else        { tPrev = t4; cPrev = 0; }
    }

    // ---- dual-threshold bisection rounds (DPP sums) ----
    int probes = 0;
    while (cHi - cLo > 64 && hiU - loU > 1u && probes < 20) {
        unsigned tAU = 0u, tBU = 0u;
        bool fell = false;
        if (cPrev > 0) {
            float g = tPrev * __fsqrt_rn((float)K / (float)cPrev);
            tAU = __float_as_uint(g * 0.88f); tBU = __float_as_uint(g * 1.18f);
        } else if (cPrev == 0) {
            tAU = __float_as_uint(tPrev * 3.0f); tBU = __float_as_uint(tPrev * 9.0f);
        } else fell = true;
        unsigned span = hiU - loU;
        if (fell || !(tAU > loU && tAU < hiU)) tAU = loU + span / 3u;
        if (tAU <= loU) tAU = loU + 1u;
        if (tAU >= hiU) tAU = hiU - 1u;
        if (fell || !(tBU >= tAU && tBU < hiU)) tBU = tAU + (hiU - tAU) / 2u;
        if (tBU < tAU) tBU = tAU;
        if (tBU >= hiU) tBU = hiU - 1u;

        float tA = __uint_as_float(tAU), tB = __uint_as_float(tBU);
        int clA = 0, clB = 0;
        #pragma unroll
        for (int r = 0; r < NREG; r++) {
            clA += (d2r[r] < tA) ? 1 : 0;
            clB += (d2r[r] < tB) ? 1 : 0;
        }
        int tot = wave_sum_dpp(clA | (clB << 16));   // sums fit 16 bits each (<= 2048)
        int cA = tot & 0xFFFF, cB = tot >> 16;

        if (cA >= K) { hiU = tAU; cHi = cA; laneHi = clA; }
        else {
            loU = tAU; cLo = cA; laneLo = clA;
            if (cB >= K) { hiU = tBU; cHi = cB; laneHi = clB; }
            else         { loU = tBU; cLo = cB; laneLo = clB; }
        }
        int dA = cA > K ? cA - K : K - cA;
        int dB = cB > K ? cB - K : K - cB;
        if (cA > 0 && dA <= dB) { tPrev = tA; cPrev = cA; }
        else                    { tPrev = tB; cPrev = cB; }
        probes++;
    }

    const float lo = __uint_as_float(loU);
    const float hi = __uint_as_float(hiU);
    const int  need = K - cLo;              // in [1, K]; window holds >= need values

    // ---- collect: counts known per lane; DPP scan -> sequential writes ----
    int c1c = laneLo;                       // # of my elems with v < lo (minus self if below)
    int c2c = laneHi - laneLo;              // # of my elems in [lo, hi)
    if (lane == (i & 63) && loU > 0u) c1c -= 1;  // self d2=0 < lo counted in laneLo
    int pk = c1c | (c2c << 16);
    int inc = wave_scan_dpp(pk);
    int excl = inc - pk;
    int tot  = __builtin_amdgcn_readlane(inc, 63);
    int b1 = excl & 0xFFFF;            // per-lane write base, below-window
    int b2 = excl >> 16;               // per-lane write base, candidates
    const int nbelow = tot & 0xFFFF;   // <= K-1
    int ecand = tot >> 16; if (ecand > 64) ecand = 64;
    #pragma unroll
    for (int r = 0; r < NREG; r++) {
        float v = d2r[r];
        int j = r * 64 + lane;
        if ((v < lo) & (j != i)) { isel[w][b1] = j; wsel[w][b1] = v; b1++; }
        else if ((v >= lo) & (v < hi)) { if (b2 < 64) candk[w][b2] = ((unsigned long long)__float_as_uint(v) << 32) | (unsigned)j; b2++; }
    }
    __builtin_amdgcn_wave_barrier();

    // ---- append `need` smallest candidates (value,index), skipping self ----
    int nsel;
    if (ecand == need && loU > 0u) {
        // fast path: window exactly fills remaining slots; self is below lo (excluded)
        if (lane < ecand) {
            int slot = nbelow + lane;
            if (slot < 64) {
                unsigned long long k2 = candk[w][lane];
                isel[w][slot] = (int)(k2 & 0xFFFFFFFFull);
                wsel[w][slot] = __uint_as_float((unsigned)(k2 >> 32));
            }
        }
        nsel = nbelow + ecand;
        if (nsel > 64) nsel = 64;
    } else {
        unsigned long long mykey = ~0ull;
        if (lane < ecand) mykey = candk[w][lane];
        int mr = 0;
        for (int u = 0; u < ecand; u++) {        // ds_read_b64 broadcast, conflict-free
            unsigned long long k2 = candk[w][u];
            mr += (k2 < mykey) ? 1 : 0;
        }
        int mj = (int)(mykey & 0xFFFFFFFFull);
        bool ps = (lane < ecand) & (mr < need) & (mj != i);
        unsigned long long ms = __ballot(ps);
        if (ps) {
            int slot = nbelow + __popcll(ms & ((1ull << lane) - 1ull));
            if (slot < 64) { isel[w][slot] = mj; wsel[w][slot] = __uint_as_float((unsigned)(mykey >> 32)); }
        }
        nsel = nbelow + __popcll(ms);
        if (nsel > 64) nsel = 64;                // expect K-1 = 39
    }
    __builtin_amdgcn_wave_barrier();
    if (lane < nsel) wsel[w][lane] = __expf(-wsel[w][lane]);
    __builtin_amdgcn_wave_barrier();

    // ---- weighted max / mean: lanes 0-21 do even m, lanes 32-53 odd m ----
    const float* fb = feats + (size_t)b * NN * PP;
    int g = lane >> 5, c = lane & 31;
    float mx = -INFINITY, sm = 0.f;
    if (c < PP) {
        #pragma unroll 8
        for (int m = g; m < nsel; m += 2) {
            int j = isel[w][m]; float wt = wsel[w][m];
            float f = fb[(size_t)j * PP + c];
            float wf = wt * f;
            mx = fmaxf(mx, wf); sm += wf;
        }
    }
    float mx2 = __shfl_xor(mx, 32, 64);
    float sm2 = __shfl_xor(sm, 32, 64);
    mx = fmaxf(mx, mx2); sm += sm2;
    if (g == 0 && c < PP) {
        urow[w][c]      = mx;
        urow[w][PP + c] = sm / (float)(K - 1);
    }
    __builtin_amdgcn_wave_barrier();

    // ---- epilogue: out[q][o] = tanh(xwo + [max|mean] . Wo[64:,o]), lanes 0-41 ----
    if (lane < OO) {
        float a0 = xw, a1 = 0.f, a2 = 0.f, a3 = 0.f;
        const float* wo = Wo + FF * OO + lane;   // rows 64..107, coalesced across lanes
        #pragma unroll
        for (int k4 = 0; k4 < (2 * PP) / 4; k4++) {
            float4 u = *((const float4*)&urow[w][k4 * 4]);   // ds_read_b128 broadcast
            a0 = fmaf(u.x, wo[(k4 * 4 + 0) * OO], a0);
            a1 = fmaf(u.y, wo[(k4 * 4 + 1) * OO], a1);
            a2 = fmaf(u.z, wo[(k4 * 4 + 2) * OO], a2);
            a3 = fmaf(u.w, wo[(k4 * 4 + 3) * OO], a3);
        }
        float acc = (a0 + a1) + (a2 + a3);
        float a = acc < -12.f ? -12.f : (acc > 12.f ? 12.f : acc);
        float e2 = __expf(2.f * a);
        out[(size_t)q * OO + lane] = (e2 - 1.f) / (e2 + 1.f);
    }
}

extern "C" void kernel_launch(void* const* d_in, const int* in_sizes, int n_in,
                              void* d_out, int out_size, void* d_ws, size_t ws_size,
                              hipStream_t stream) {
    const float* x  = (const float*)d_in[0];
    const float* Ws = (const float*)d_in[1];
    const float* bs = (const float*)d_in[2];
    const float* Wf = (const float*)d_in[3];
    const float* bf = (const float*)d_in[4];
    const float* Wo = (const float*)d_in[5];
    const float* bo = (const float*)d_in[6];
    const int*   nn = (const int*)d_in[7];
    float* out = (float*)d_out;

    float* coords = (float*)d_ws;                              // 16*2048*4  = 512 KB
    float* feats  = coords + (size_t)BB * NN * SS;             // 16*2048*22 = 2.75 MB
    float* xwo    = feats  + (size_t)BB * NN * PP;             // 32768*42   = 5.5 MB

    prep_kernel<<<XBLK, 256, 0, stream>>>(x, Ws, bs, Wf, bf, Wo, bo, coords, feats, xwo);
    knn_out_kernel<<<(BB * NN) / 2, 128, 0, stream>>>(coords, feats, xwo, Wo, nn, out);
}